// Round 11
// baseline (167.525 us; speedup 1.0000x reference)
//
#include <hip/hip_runtime.h>
#include <hip/hip_fp16.h>

#define FSIZE   768
#define TW0     769
#define TW1     193
#define COL1    576
#define NPAIRS  300000
#define NCODES  30000
#define NROWS   8192
#define NCB     32768

// main grid: task0 = 64 pairs/wave (4 groups x 16-pair spans)
#define NB0     1176                        // task0 blocks (div by 8): 4704 waves
#define NB1     1176                        // task1 blocks (div by 8)
#define NGRID   (NB0 + NB1)
#define NPART   NGRID                       // (fallback only)

// fused pre-pass v2: fat grid-stride sections; hist first
#define PB_H    512
#define PB_F    512
#define PB_W0   1024
#define PB_W1   256
#define NPRE    (PB_H + PB_F + PB_W0 + PB_W1)   // 2304
#define S_H     (PB_H)
#define S_F     (PB_H + PB_F)
#define S_W0    (PB_H + PB_F + PB_W0)
#define FEAT_U4 393216                      // 8192*768/16
#define W0_U4   1440000                     // 30000*48
#define W1_U4   360000                      // 30000*12

// ws layout in 4-byte units
#define O_FEAT8  ((size_t)0)
#define O_W08    (O_FEAT8 + 1572864)
#define O_W18    (O_W08 + 5760000)
#define O_B0F    (O_W18 + 1440000)
#define O_B1F    (O_B0F + 30000)
#define O_CNT    (O_B1F + 30000)
#define O_CUR    (O_CNT + 65536)
#define O_SREC   (O_CUR + 65536)
#define O_PART   (O_SREC + 2400000)
#define WS_U32   (O_PART + NPART + 64)

#define FSCALE   16.0f
#define WSCALE   64.0f
#define DESCALE  (1.0f / 1024.0f)

typedef float f32x2_t __attribute__((ext_vector_type(2)));

__device__ __forceinline__ float loss_term(float x, float y) {
    float ax = fabsf(x);
    return fmaxf(x, 0.0f) + log1pf(__expf(-ax)) - x * y;
}

__device__ __forceinline__ float4 ld4u(const float* p) {
    float4 v; __builtin_memcpy(&v, p, 16); return v;
}

#if defined(__has_builtin)
# if __has_builtin(__builtin_amdgcn_cvt_pk_f32_fp8)
#  define HW_FP8_DEC 1
# endif
# if __has_builtin(__builtin_amdgcn_cvt_pk_fp8_f32)
#  define HW_FP8_ENC 1
# endif
#endif

__device__ __forceinline__ float sw_fp8_to_f32(unsigned b) {
    unsigned mag = b & 0x7fu;
    unsigned r = ((b & 0x80u) << 24) | ((mag << 20) + 0x3C000000u);
    float f = __uint_as_float(r);
    return mag ? f : 0.0f;
}

template <bool HI>
__device__ __forceinline__ f32x2_t fp8x2_to_f32(unsigned u) {
#ifdef HW_FP8_DEC
    return __builtin_amdgcn_cvt_pk_f32_fp8(u, HI);
#else
    f32x2_t o;
    unsigned lo8 = HI ? ((u >> 16) & 0xffu) : (u & 0xffu);
    unsigned hi8 = HI ? ((u >> 24) & 0xffu) : ((u >> 8) & 0xffu);
    o[0] = sw_fp8_to_f32(lo8);
    o[1] = sw_fp8_to_f32(hi8);
    return o;
#endif
}

__device__ __forceinline__ unsigned sw_f32_to_fp8(float x) {
    unsigned short h = __half_as_ushort(__float2half(x));
    unsigned s = ((unsigned)h >> 8) & 0x80u;
    int e = (h >> 10) & 31;
    unsigned m = h & 1023u;
    if (e >= 23) return s | 0x7eu;
    if (e < 9)  return s;
    unsigned t = ((unsigned)(e - 8) << 3) | (m >> 7);
    unsigned rnd = (m >> 6) & 1u, sticky = (m & 63u) ? 1u : 0u;
    t += (rnd & (sticky | (t & 1u)));
    if (t > 0x7eu) t = 0x7eu;
    return s | t;
}

__device__ __forceinline__ unsigned f32x4_to_fp8(float a, float b, float c, float d) {
#ifdef HW_FP8_ENC
    int u = __builtin_amdgcn_cvt_pk_fp8_f32(a, b, 0, false);
    u = __builtin_amdgcn_cvt_pk_fp8_f32(c, d, u, true);
    return (unsigned)u;
#else
    return sw_f32_to_fp8(a) | (sw_f32_to_fp8(b) << 8)
         | (sw_f32_to_fp8(c) << 16) | (sw_f32_to_fp8(d) << 24);
#endif
}

__device__ __forceinline__ uint4 enc16(const float* s, float sc) {
    float4 a = ld4u(s), b = ld4u(s + 4), c = ld4u(s + 8), d = ld4u(s + 12);
    uint4 o;
    o.x = f32x4_to_fp8(a.x * sc, a.y * sc, a.z * sc, a.w * sc);
    o.y = f32x4_to_fp8(b.x * sc, b.y * sc, b.z * sc, b.w * sc);
    o.z = f32x4_to_fp8(c.x * sc, c.y * sc, c.z * sc, c.w * sc);
    o.w = f32x4_to_fp8(d.x * sc, d.y * sc, d.z * sc, d.w * sc);
    return o;
}

__device__ __forceinline__ float dot16(uint4 u, const float* w, float s) {
    f32x2_t p;
    p = fp8x2_to_f32<false>(u.x); s += p[0] * w[0]  + p[1] * w[1];
    p = fp8x2_to_f32<true >(u.x); s += p[0] * w[2]  + p[1] * w[3];
    p = fp8x2_to_f32<false>(u.y); s += p[0] * w[4]  + p[1] * w[5];
    p = fp8x2_to_f32<true >(u.y); s += p[0] * w[6]  + p[1] * w[7];
    p = fp8x2_to_f32<false>(u.z); s += p[0] * w[8]  + p[1] * w[9];
    p = fp8x2_to_f32<true >(u.z); s += p[0] * w[10] + p[1] * w[11];
    p = fp8x2_to_f32<false>(u.w); s += p[0] * w[12] + p[1] * w[13];
    p = fp8x2_to_f32<true >(u.w); s += p[0] * w[14] + p[1] * w[15];
    return s;
}

__device__ __forceinline__ float dot8(uint2 u, const float* w, float s) {
    f32x2_t p;
    p = fp8x2_to_f32<false>(u.x); s += p[0] * w[0] + p[1] * w[1];
    p = fp8x2_to_f32<true >(u.x); s += p[0] * w[2] + p[1] * w[3];
    p = fp8x2_to_f32<false>(u.y); s += p[0] * w[4] + p[1] * w[5];
    p = fp8x2_to_f32<true >(u.y); s += p[0] * w[6] + p[1] * w[7];
    return s;
}

__device__ __forceinline__ void unpack16(uint4 u, float* w) {
    f32x2_t p;
    p = fp8x2_to_f32<false>(u.x); w[0]  = p[0]; w[1]  = p[1];
    p = fp8x2_to_f32<true >(u.x); w[2]  = p[0]; w[3]  = p[1];
    p = fp8x2_to_f32<false>(u.y); w[4]  = p[0]; w[5]  = p[1];
    p = fp8x2_to_f32<true >(u.y); w[6]  = p[0]; w[7]  = p[1];
    p = fp8x2_to_f32<false>(u.z); w[8]  = p[0]; w[9]  = p[1];
    p = fp8x2_to_f32<true >(u.z); w[10] = p[0]; w[11] = p[1];
    p = fp8x2_to_f32<false>(u.w); w[12] = p[0]; w[13] = p[1];
    p = fp8x2_to_f32<true >(u.w); w[14] = p[0]; w[15] = p[1];
}

__device__ __forceinline__ void unpack8(uint2 u, float* w) {
    f32x2_t p;
    p = fp8x2_to_f32<false>(u.x); w[0] = p[0]; w[1] = p[1];
    p = fp8x2_to_f32<true >(u.x); w[2] = p[0]; w[3] = p[1];
    p = fp8x2_to_f32<false>(u.y); w[4] = p[0]; w[5] = p[1];
    p = fp8x2_to_f32<true >(u.y); w[6] = p[0]; w[7] = p[1];
}

__global__ __launch_bounds__(256) void zero_cnt_kernel(int* __restrict__ cnt) {
    cnt[blockIdx.x * 256 + threadIdx.x] = 0;   // 256 blocks = 65536 ints
}

// Fused pre-pass v2: fat grid-stride sections. hist | feat | w0 | w1
__global__ __launch_bounds__(256) void fused_pre_kernel(
    const float* __restrict__ feat, const float* __restrict__ w0,
    const float* __restrict__ w1,
    const int* __restrict__ idx0, const int* __restrict__ idx1,
    uint4* __restrict__ feat8, uint4* __restrict__ w08, uint4* __restrict__ w18,
    float* __restrict__ b0f, float* __restrict__ b1f, int* __restrict__ cnt)
{
    const int bid = blockIdx.x;
    if (bid < S_H) {
        const int tid = bid * 256 + threadIdx.x;          // stride 131072
#pragma unroll
        for (int k = 0; k < 5; ++k) {
            const int i = tid + k * (PB_H * 256);
            if (i < 2 * NPAIRS) {
                if (i < NPAIRS) atomicAdd(&cnt[idx0[2 * i + 1]], 1);
                else            atomicAdd(&cnt[NCB + idx1[2 * (i - NPAIRS) + 1]], 1);
            }
        }
    } else if (bid < S_F) {
        const int tid = (bid - S_H) * 256 + threadIdx.x;  // stride 131072
#pragma unroll
        for (int k = 0; k < 3; ++k) {
            const int i = tid + k * (PB_F * 256);         // < 393216 always
            feat8[i] = enc16(feat + (size_t)i * 16, FSCALE);
        }
    } else if (bid < S_W0) {
        const int tid = (bid - S_F) * 256 + threadIdx.x;  // stride 262144
#pragma unroll
        for (int k = 0; k < 6; ++k) {
            const int i = tid + k * (PB_W0 * 256);
            if (i < W0_U4) {
                const int c = i / 48;
                const int e = (i - c * 48) * 16;
                const float* src = w0 + (size_t)c * TW0 + e;
                w08[i] = enc16(src, WSCALE);
                if (e == 0) b0f[c] = src[FSIZE];
            }
        }
    } else {
        const int tid = (bid - S_W0) * 256 + threadIdx.x; // stride 65536
#pragma unroll
        for (int k = 0; k < 6; ++k) {
            const int i = tid + k * (PB_W1 * 256);
            if (i < W1_U4) {
                const int c = i / 12;
                const int e = (i - c * 12) * 16;
                const float* src = w1 + (size_t)c * TW1 + e;
                w18[i] = enc16(src, WSCALE);
                if (e == 0) b1f[c] = src[TW1 - 1];
            }
        }
    }
}

// Exclusive scan over 65536 bins (task1 cumulative lands at [NPAIRS, 2*NPAIRS))
__global__ __launch_bounds__(1024) void scan2_kernel(const int* __restrict__ cnt,
                                                     int* __restrict__ cursor) {
    __shared__ int wsum[16];
    __shared__ int wbase[16];
    const int t = threadIdx.x;
    const int lane = t & 63, wv = t >> 6;
    const int4* c4 = (const int4*)cnt + (size_t)t * 16;
    int4 v[16];
#pragma unroll
    for (int j = 0; j < 16; ++j) v[j] = c4[j];
    int s = 0;
#pragma unroll
    for (int j = 0; j < 16; ++j) {
        int a;
        a = v[j].x; v[j].x = s; s += a;
        a = v[j].y; v[j].y = s; s += a;
        a = v[j].z; v[j].z = s; s += a;
        a = v[j].w; v[j].w = s; s += a;
    }
    int incl = s;
#pragma unroll
    for (int off = 1; off < 64; off <<= 1) {
        int u = __shfl_up(incl, off, 64);
        if (lane >= off) incl += u;
    }
    if (lane == 63) wsum[wv] = incl;
    __syncthreads();
    if (wv == 0 && lane < 16) {
        int mysum = wsum[lane];
        int winc = mysum;
#pragma unroll
        for (int off = 1; off < 16; off <<= 1) {
            int u = __shfl_up(winc, off, 64);
            if (lane >= off) winc += u;
        }
        wbase[lane] = winc - mysum;
    }
    __syncthreads();
    const int base = wbase[wv] + incl - s;
    int4* cu = (int4*)cursor + (size_t)t * 16;
#pragma unroll
    for (int j = 0; j < 16; ++j)
        cu[j] = make_int4(base + v[j].x, base + v[j].y, base + v[j].z, base + v[j].w);
}

// Scatter both tasks into one 600k-record array {r, c, y_bits, p}; zero loss slot
__global__ __launch_bounds__(256) void scatter2_kernel(
    const int* __restrict__ idx0, const float* __restrict__ y0,
    const int* __restrict__ idx1, const float* __restrict__ y1,
    int* __restrict__ cursor, uint4* __restrict__ srec, float* __restrict__ loss_out)
{
    const int tid = blockIdx.x * 256 + threadIdx.x;       // 1172 blocks, stride 300032
    if (tid == 0) loss_out[0] = 0.0f;
#pragma unroll
    for (int k = 0; k < 2; ++k) {
        const int t = tid + k * 300032;
        if (t < NPAIRS) {
            int r = idx0[2 * t], c = idx0[2 * t + 1];
            int pos = atomicAdd(&cursor[c], 1);
            srec[pos] = make_uint4((unsigned)r, (unsigned)c, __float_as_uint(y0[t]), (unsigned)t);
        } else if (t < 2 * NPAIRS) {
            int p = t - NPAIRS;
            int r = idx1[2 * p], c = idx1[2 * p + 1];
            int pos = atomicAdd(&cursor[NCB + c], 1);
            srec[pos] = make_uint4((unsigned)r, (unsigned)c, __float_as_uint(y1[p]), (unsigned)p);
        }
    }
}

// Main: task0 blocks [0,NB0): 4x 16-lane groups, 16-pair sorted spans each
// (64 pairs/wave), fp8 w0 unpacked to 48 f32 regs per code-run, XCD-partitioned.
//       task1 blocks [NB0,NGRID): 8x 8-lane groups, 8-pair spans, fp8 w1.
// Block loss sums atomically accumulate into loss_out (zeroed by scatter2).
__global__ __launch_bounds__(256) void main3_kernel(
    const unsigned char* __restrict__ feat8, const unsigned char* __restrict__ w08,
    const unsigned char* __restrict__ w18,
    const float* __restrict__ b0f, const float* __restrict__ b1f,
    const uint4* __restrict__ srec,
    float* __restrict__ out_final, float* __restrict__ loss_out)
{
    __shared__ float bsum[4];
    const int lane = threadIdx.x & 63;
    const int wv   = threadIdx.x >> 6;
    float wavesum = 0.f;

    if (blockIdx.x < NB0) {
        const int work = (blockIdx.x & 7) * (NB0 / 8) + (blockIdx.x >> 3);
        const int wid = work * 4 + wv;
        const int g = lane >> 4, sub = lane & 15;
        const int mypair = wid * 64 + 16 * g + sub;
        int rdidx = mypair < NPAIRS ? mypair : NPAIRS - 1;
        const uint4 rec = srec[rdidx];
        int prev_c = -1;
        float wc[48];
        float wb = 0.f, lg = 0.f;
#pragma unroll
        for (int j = 0; j < 16; ++j) {
            const bool valid = (wid * 64 + 16 * g + j) < NPAIRS;   // group-uniform
            if (valid) {
                const int src = (lane & 48) | j;
                const int r = __shfl((int)rec.x, src, 64);
                const int c = __shfl((int)rec.y, src, 64);
                if (c != prev_c) {                       // group-uniform
                    prev_c = c;
                    const unsigned char* wr = w08 + (size_t)c * FSIZE + 48 * sub;
                    uint4 wu0 = *(const uint4*)wr;
                    uint4 wu1 = *(const uint4*)(wr + 16);
                    uint4 wu2 = *(const uint4*)(wr + 32);
                    unpack16(wu0, &wc[0]);
                    unpack16(wu1, &wc[16]);
                    unpack16(wu2, &wc[32]);
                    wb = b0f[c];
                }
                const unsigned char* fr = feat8 + (size_t)r * FSIZE + 48 * sub;
                uint4 f0 = *(const uint4*)fr;
                uint4 f1 = *(const uint4*)(fr + 16);
                uint4 f2 = *(const uint4*)(fr + 32);
                float s = dot16(f0, &wc[0], 0.f);
                s = dot16(f1, &wc[16], s);
                s = dot16(f2, &wc[32], s);
                s += __shfl_xor(s, 8, 64);
                s += __shfl_xor(s, 4, 64);
                s += __shfl_xor(s, 2, 64);
                s += __shfl_xor(s, 1, 64);
                lg = (sub == j) ? s * DESCALE + wb : lg;
            }
        }
        float ll = 0.f;
        if (mypair < NPAIRS) {
            out_final[rec.w] = lg;
            ll = loss_term(lg, __uint_as_float(rec.z));
        }
#pragma unroll
        for (int m = 32; m; m >>= 1) ll += __shfl_xor(ll, m, 64);
        wavesum = ll;
    } else {
        const int tb = blockIdx.x - NB0;
        const int work1 = (tb & 7) * (NB1 / 8) + (tb >> 3);
        const long base = (long)(work1 * 4 + wv) * 64;
        if (base < NPAIRS) {
            const int g = lane >> 3, sub = lane & 7;
            long lpos = base + 8 * g + sub;
            if (lpos > NPAIRS - 1) lpos = NPAIRS - 1;
            const uint4 rec = srec[(size_t)NPAIRS + lpos];
            int prev_c = -1;
            float wc[24];
            float wb = 0.f, lg = 0.f;
#pragma unroll
            for (int j = 0; j < 8; ++j) {
                const bool valid = (base + 8 * g + j) < NPAIRS;  // group-uniform
                const int src = (lane & 56) | j;
                const int r = __shfl((int)rec.x, src, 64);
                const int c = __shfl((int)rec.y, src, 64);
                if (valid) {
                    if (c != prev_c) {
                        prev_c = c;
                        const unsigned char* wr = w18 + (size_t)c * 192 + 24 * sub;
                        uint2 wu0 = *(const uint2*)wr;
                        uint2 wu1 = *(const uint2*)(wr + 8);
                        uint2 wu2 = *(const uint2*)(wr + 16);
                        unpack8(wu0, &wc[0]);
                        unpack8(wu1, &wc[8]);
                        unpack8(wu2, &wc[16]);
                        wb = b1f[c];
                    }
                    const unsigned char* fr = feat8 + (size_t)r * FSIZE + COL1 + 24 * sub;
                    uint2 f0 = *(const uint2*)fr;
                    uint2 f1 = *(const uint2*)(fr + 8);
                    uint2 f2 = *(const uint2*)(fr + 16);
                    float s = dot8(f0, &wc[0], 0.f);
                    s = dot8(f1, &wc[8], s);
                    s = dot8(f2, &wc[16], s);
                    s += __shfl_xor(s, 4, 64);
                    s += __shfl_xor(s, 2, 64);
                    s += __shfl_xor(s, 1, 64);
                    lg = (sub == j) ? s * DESCALE + wb : lg;
                }
            }
            float ll = 0.f;
            if ((base + 8 * g + sub) < NPAIRS)
                ll = loss_term(lg, __uint_as_float(rec.z));
#pragma unroll
            for (int m = 32; m; m >>= 1) ll += __shfl_xor(ll, m, 64);
            wavesum = ll;
        }
    }

    if (lane == 0) bsum[wv] = wavesum;
    __syncthreads();
    if (threadIdx.x == 0) {
        float t = bsum[0] + bsum[1] + bsum[2] + bsum[3];
        atomicAdd(loss_out, t);
    }
}

__global__ __launch_bounds__(1024) void reduce_kernel(
    const float* __restrict__ partial, int n, float* __restrict__ out)
{
    __shared__ float sh[1024];
    float s = 0.0f;
    for (int i = threadIdx.x; i < n; i += 1024) s += partial[i];
    sh[threadIdx.x] = s;
    __syncthreads();
    for (int off = 512; off; off >>= 1) {
        if ((int)threadIdx.x < off) sh[threadIdx.x] += sh[threadIdx.x + off];
        __syncthreads();
    }
    if (threadIdx.x == 0) out[0] = sh[0];
}

// ---------------- fallback (all-f32, unsorted, small ws) ----------------
__global__ __launch_bounds__(256) void task0_kernel(
    const float* __restrict__ feat, const float* __restrict__ wt,
    const int* __restrict__ idx, const float* __restrict__ y,
    float* __restrict__ out_final, float* __restrict__ partial)
{
    __shared__ float lsum[4];
    const int lane = threadIdx.x & 63;
    const int wv = threadIdx.x >> 6;
    const int pair = blockIdx.x * 4 + wv;
    const int r = idx[2 * pair];
    const int c = idx[2 * pair + 1];
    const float4* f4 = (const float4*)(feat + (size_t)r * FSIZE);
    const float* wrow = wt + (size_t)c * TW0;
    float s = 0.0f;
#pragma unroll
    for (int k = 0; k < 3; ++k) {
        const int j = lane + (k << 6);
        float4 f = f4[j];
        float4 w = ld4u(wrow + 4 * j);
        s += f.x * w.x + f.y * w.y + f.z * w.z + f.w * w.w;
    }
#pragma unroll
    for (int m = 32; m; m >>= 1) s += __shfl_xor(s, m, 64);
    if (lane == 0) {
        const float logit = s + wrow[FSIZE];
        out_final[pair] = logit;
        lsum[wv] = loss_term(logit, y[pair]);
    }
    __syncthreads();
    if (threadIdx.x == 0)
        partial[blockIdx.x] = lsum[0] + lsum[1] + lsum[2] + lsum[3];
}

__global__ __launch_bounds__(256) void task1_kernel(
    const float* __restrict__ feat, const float* __restrict__ wt,
    const int* __restrict__ idx, const float* __restrict__ y,
    float* __restrict__ partial)
{
    __shared__ float lsum[16];
    const int lane = threadIdx.x & 63;
    const int wv = threadIdx.x >> 6;
    const int sub = lane & 15;
    const int pg = lane >> 4;
    const int pair = (blockIdx.x * 4 + wv) * 4 + pg;
    const int r = idx[2 * pair];
    const int c = idx[2 * pair + 1];
    const float4* f4 = (const float4*)(feat + (size_t)r * FSIZE + COL1);
    const float* wrow = wt + (size_t)c * TW1;
    float s = 0.0f;
#pragma unroll
    for (int k = 0; k < 3; ++k) {
        const int j = sub + (k << 4);
        float4 f = f4[j];
        float4 w = ld4u(wrow + 4 * j);
        s += f.x * w.x + f.y * w.y + f.z * w.z + f.w * w.w;
    }
#pragma unroll
    for (int m = 8; m; m >>= 1) s += __shfl_xor(s, m, 64);
    if (sub == 0) {
        const float logit = s + wrow[TW1 - 1];
        lsum[wv * 4 + pg] = loss_term(logit, y[pair]);
    }
    __syncthreads();
    if (threadIdx.x == 0) {
        float t = 0.0f;
#pragma unroll
        for (int i = 0; i < 16; ++i) t += lsum[i];
        partial[blockIdx.x] = t;
    }
}

extern "C" void kernel_launch(void* const* d_in, const int* in_sizes, int n_in,
                              void* d_out, int out_size, void* d_ws, size_t ws_size,
                              hipStream_t stream) {
    const float* feat = (const float*)d_in[0];
    const float* w0   = (const float*)d_in[1];
    const float* w1   = (const float*)d_in[2];
    const int*   idx0 = (const int*)d_in[3];
    const float* y0   = (const float*)d_in[4];
    const int*   idx1 = (const int*)d_in[6];
    const float* y1   = (const float*)d_in[7];

    float* out = (float*)d_out;
    unsigned* ws = (unsigned*)d_ws;

    if (ws_size >= WS_U32 * 4) {
        unsigned char* feat8 = (unsigned char*)(ws + O_FEAT8);
        unsigned char* w08   = (unsigned char*)(ws + O_W08);
        unsigned char* w18   = (unsigned char*)(ws + O_W18);
        float* b0f   = (float*)(ws + O_B0F);
        float* b1f   = (float*)(ws + O_B1F);
        int*   cnt   = (int*)(ws + O_CNT);
        int*   cursor= (int*)(ws + O_CUR);
        uint4* srec  = (uint4*)(ws + O_SREC);

        zero_cnt_kernel<<<256, 256, 0, stream>>>(cnt);
        fused_pre_kernel<<<NPRE, 256, 0, stream>>>(
            feat, w0, w1, idx0, idx1,
            (uint4*)feat8, (uint4*)w08, (uint4*)w18, b0f, b1f, cnt);
        scan2_kernel<<<1, 1024, 0, stream>>>(cnt, cursor);
        scatter2_kernel<<<1172, 256, 0, stream>>>(
            idx0, y0, idx1, y1, cursor, srec, out + NPAIRS);
        main3_kernel<<<NGRID, 256, 0, stream>>>(
            feat8, w08, w18, b0f, b1f, srec, out, out + NPAIRS);
    } else {
        float* part = (float*)ws;
        const int nb0 = NPAIRS / 4;
        const int nb1 = NPAIRS / 16;
        task0_kernel<<<nb0, 256, 0, stream>>>(feat, w0, idx0, y0, out, part);
        task1_kernel<<<nb1, 256, 0, stream>>>(feat, w1, idx1, y1, part + nb0);
        reduce_kernel<<<1, 1024, 0, stream>>>(part, nb0 + nb1, out + NPAIRS);
    }
}